// Round 7
// baseline (364.816 us; speedup 1.0000x reference)
//
#include <hip/hip_runtime.h>

#define N_NODES 50000
#define N_EDGES 800000
#define IN_FEAT 512
#define OUT_FEAT 128

#define GEMM_BLOCKS ((N_NODES + 31) / 32)            // 1563 (BM=32)
#define ROWPTR_BLOCKS ((N_NODES + 1 + 63) / 64)      // 782 blocks of 64 thr

// NUMERICS CONTRACT (R3 post-mortem): the harness's np reference is matched
// bit-for-bit through the multispike quantizer ONLY when fp32 accumulation
// order is strictly sequential (k-order in GEMM, edge-order in SPMM).
// Do NOT split accumulator chains. Zero-padding with w=0 is bit-exact.
//
// R5/R6 HARD RULE: no multi-float4 register array held across a loop
// boundary alongside the accumulators (spills).
// R7: in-block pipelining (reg-prefetch, A-direct, DMA dbuf) all lost to
// the plain 2-barrier loop; cross-block overlap is the only latency-hiding
// that works here.
// R9: spmm is fabric-BW bound at ~3 TB/s on 410MB of irreducible gather
// traffic (8->16-deep MLP probe was neutral). spmm FROZEN.
// R10 post-mortem: 6 blocks/CU killed the latency exposure (R4's ~54us gap
// -> ~10us) but the 4x8 tile saturated the LDS pipe (3 reads/32 FMAs;
// wall == LDS demand within 3%). R11: keep 6 blocks/CU, restore the 8x8
// tile's 4-reads/64-FMAs ratio via 64-thread single-wave blocks
// (BM=32, BN=128). Single-wave blocks also make barriers self-satisfied.

__device__ __forceinline__ float multispike(float a) {
    // floor(clamp(4x, 0, 4) + 0.5) / 4
    return floorf(fminf(fmaxf(4.0f * a, 0.0f), 4.0f) + 0.5f) * 0.25f;
}

// ---------------------------------------------------------------------------
// GEMM: C[M,128] = A[M,512] @ B[512,128], fp32 vector FMA.
// BM=32, BN=128, BK=32. 64 threads (1 wave). Thread tile 8x8.
// Blocks [0, GEMM_BLOCKS): gemm. [GEMM_BLOCKS, +ROWPTR_BLOCKS): fused
// row_ptr binary search (no LDS, no barriers, exits early -> no hazard).
// - As[32][36]: transposed store (16 scalar stores/thread, 4-way conflict,
//   same pattern as R4/R10); read 2x b128 at [k][ty*8], 4 distinct bank-
//   quads across the wave (ty in 0..3), 16-lane broadcast, conflict-free.
// - Bs XOR quad-swizzle bswz(q)=q^((q>>3)&1) on store and load (R4-
//   verified: makes the tx-stride-32B read aliasing 2-way = free).
// - Per-thread k-chain for each (m,n) runs k=0..511 strictly ascending ->
//   bit-exact vs reference.
// ---------------------------------------------------------------------------
__device__ __forceinline__ int bswz(int q) { return q ^ ((q >> 3) & 1); }

__global__ __launch_bounds__(64) void gemm_rowptr_kernel(
    const float* __restrict__ A, const float* __restrict__ B,
    float* __restrict__ C, int M,
    const int* __restrict__ rows, int* __restrict__ row_ptr) {
    __shared__ float As[32][36];    // [k][m], padded
    __shared__ float Bs[32][128];   // [k][n], quad-swizzled

    const int tid = threadIdx.x;

    if (blockIdx.x >= GEMM_BLOCKS) {
        // ---- fused rowptr: binary search, no LDS, no barriers.
        int i = (blockIdx.x - GEMM_BLOCKS) * 64 + tid;
        if (i <= N_NODES) {
            int lo = 0, hi = N_EDGES;
            while (lo < hi) {
                int mid = (lo + hi) >> 1;
                if (rows[mid] < i) lo = mid + 1; else hi = mid;
            }
            row_ptr[i] = lo;
        }
        return;
    }

    const int tx = tid & 15;   // n0 = tx*8 (16 groups cover 128)
    const int ty = tid >> 4;   // 0..3, m0 = ty*8 (4 groups cover 32)
    const int block_m = blockIdx.x * 32;

    const int bq0 = bswz(2 * tx) * 4;
    const int bq1 = bswz(2 * tx + 1) * 4;

    float acc[8][8];
#pragma unroll
    for (int i = 0; i < 8; i++)
#pragma unroll
        for (int j = 0; j < 8; j++) acc[i][j] = 0.0f;

    for (int k0 = 0; k0 < IN_FEAT; k0 += 32) {
        // Stage A tile: 32 rows x 32 k = 256 float4 / 64 threads = 4 each.
        // Lanes: 8 consecutive lanes cover 128B of one row -> coalesced.
#pragma unroll
        for (int i = 0; i < 4; i++) {
            int f = tid + i * 64;
            int r = f >> 3;             // 0..31
            int kq = (f & 7) << 2;
            int gm = block_m + r;
            float4 v = make_float4(0.f, 0.f, 0.f, 0.f);
            if (gm < M) v = *(const float4*)(A + (size_t)gm * IN_FEAT + k0 + kq);
            As[kq + 0][r] = v.x;
            As[kq + 1][r] = v.y;
            As[kq + 2][r] = v.z;
            As[kq + 3][r] = v.w;
        }
        // Stage B tile: 32 rows x 128 n = 1024 float4 / 64 threads = 16 each.
        // Lanes: 32 consecutive lanes cover one 512B row -> coalesced.
#pragma unroll
        for (int i = 0; i < 16; i++) {
            int f = tid + i * 64;
            int r = f >> 5;
            int q = f & 31;
            *(float4*)&Bs[r][bswz(q) * 4] =
                *(const float4*)(B + (size_t)(k0 + r) * OUT_FEAT + q * 4);
        }
        __syncthreads();   // single-wave block: self-satisfied, drains cnts

#pragma unroll
        for (int k = 0; k < 32; k++) {
            float4 a0 = *(const float4*)&As[k][ty * 8];
            float4 a1 = *(const float4*)&As[k][ty * 8 + 4];
            float4 b0 = *(const float4*)&Bs[k][bq0];
            float4 b1 = *(const float4*)&Bs[k][bq1];
            float av[8] = {a0.x, a0.y, a0.z, a0.w, a1.x, a1.y, a1.z, a1.w};
            float bv[8] = {b0.x, b0.y, b0.z, b0.w, b1.x, b1.y, b1.z, b1.w};
#pragma unroll
            for (int i = 0; i < 8; i++)
#pragma unroll
                for (int j = 0; j < 8; j++)
                    acc[i][j] = fmaf(av[i], bv[j], acc[i][j]);
        }
        __syncthreads();
    }

#pragma unroll
    for (int i = 0; i < 8; i++) {
        int gm = block_m + ty * 8 + i;
        if (gm < M) {
            float* cp = C + (size_t)gm * OUT_FEAT + tx * 8;
            *(float4*)cp = make_float4(acc[i][0], acc[i][1], acc[i][2], acc[i][3]);
            *(float4*)(cp + 4) = make_float4(acc[i][4], acc[i][5], acc[i][6], acc[i][7]);
        }
    }
}

// ---------------------------------------------------------------------------
// SPMM + multispike (FROZEN, R9): one wave per output row, lane l owns
// float2 l. 16-deep gather pipeline, zero-padded (w=0 slots are bit-exact
// no-ops), ONE strict e-order FMA chain per accumulator.
// ---------------------------------------------------------------------------
__global__ __launch_bounds__(256) void spmm_kernel(const float* __restrict__ x,
                                                   const int* __restrict__ cols,
                                                   const float* __restrict__ ew,
                                                   const int* __restrict__ row_ptr,
                                                   float* __restrict__ out) {
    const int wave = threadIdx.x >> 6;
    const int lane = threadIdx.x & 63;
    const int r = blockIdx.x * 4 + wave;
    if (r >= N_NODES) return;

    const int e0 = row_ptr[r];
    const int e1 = row_ptr[r + 1];
    const int niter = (e1 - e0 + 15) >> 4;   // zero-padded to multiple of 16
    const float2* __restrict__ x2 = (const float2*)x;

    float accx = 0.0f, accy = 0.0f;

    for (int t = 0; t < niter; t++) {
        const int base = e0 + t * 16;
        int c[16];
        float w[16];
#pragma unroll
        for (int j = 0; j < 16; j++) {
            int e = base + j;
            int ee = (e < e1) ? e : (e1 - 1);
            c[j] = cols[ee];
            w[j] = (e < e1) ? ew[ee] : 0.0f;
        }
        float2 v[16];
#pragma unroll
        for (int j = 0; j < 16; j++) {
            v[j] = x2[(size_t)c[j] * 64 + lane];
        }
#pragma unroll
        for (int j = 0; j < 16; j++) {   // strict e-order accumulation
            accx = fmaf(w[j], v[j].x, accx);
            accy = fmaf(w[j], v[j].y, accy);
        }
    }

    float2* out2 = (float2*)out;
    out2[(size_t)r * 64 + lane] = make_float2(multispike(accx), multispike(accy));
}

extern "C" void kernel_launch(void* const* d_in, const int* in_sizes, int n_in,
                              void* d_out, int out_size, void* d_ws, size_t ws_size,
                              hipStream_t stream) {
    const float* feat = (const float*)d_in[0];   // [50000, 512]
    const float* weight = (const float*)d_in[1]; // [512, 128]
    const int* rows = (const int*)d_in[2];       // [800000] sorted
    const int* cols = (const int*)d_in[3];       // [800000]
    const float* ew = (const float*)d_in[4];     // [800000]
    float* out = (float*)d_out;                  // [50000, 128]

    // Workspace layout: x [50000*128 f32] then row_ptr [50001 i32]
    float* x = (float*)d_ws;
    int* row_ptr = (int*)((char*)d_ws + (size_t)N_NODES * OUT_FEAT * sizeof(float));

    gemm_rowptr_kernel<<<GEMM_BLOCKS + ROWPTR_BLOCKS, 64, 0, stream>>>(
        feat, weight, x, N_NODES, rows, row_ptr);
    spmm_kernel<<<(N_NODES + 3) / 4, 256, 0, stream>>>(x, cols, ew, row_ptr, out);
}